// Round 15
// baseline (63.321 us; speedup 1.0000x reference)
//
#include <hip/hip_runtime.h>
#include <hip/hip_bf16.h>

// TSM temporal shift + 1x1 conv (256->256) fused as bf16 MFMA GEMM.
// x: [128, 256, 28, 28] f32, w: [256, 256] f32, out: [128, 256, 28, 28] f32.
// out[n,o,p] = sum_c W[o,c] * Y_n[c,p],
//   Y_n[c,p] = x[n-1,c,p] (c<32, t>0), x[n+1,c,p] (32<=c<64, t<7), x[n,c,p] else.
//
// R15: 512-thread single-staging full-o blocks.
//  R13/R14 failed because one 256-thr block doing 2x compute per staging
//  halves memory duty at 2 blocks/CU. This keeps R10's per-wave workload
//  IDENTICAL (32 o x 112 px, 112 MFMA, K-split wf) but uses 8 waves/block:
//  all 256 o from ONE staging of x (waves 0-3 stage c<128, 4-7 stage c>=128;
//  per-thread channel-pair -> wave-uniform fold region). 205MB CU-side
//  (vs R10's 306) AND 16 waves/CU (vs R10's 8).
//  - Staging: thread (cpg=tid>>2, pvs=tid&3) owns channel pair 2cpg and 28
//    pixels; 14 asm loads; vmcnt(8) leaves wfA flying; one barrier.
//  - wf K-split (wf[4][2]=32 regs): wfA in prologue; wfB issued after pass1
//    (WAR-safe: MFMA reads at issue, program order). Peak live ~103 < 128.
//  - R10-verified 4-bf16 swizzle pair; swapped-operand MFMA (D[p,o]) ->
//    14 dwordx4 stores; plain stores at end (R11 lesson).

#define CDIM 256
#define HWPX 784
#define FRST (CDIM * HWPX)        // 200704 floats per frame
#define P_TILE 112
#define NPT  7                    // 112-px tiles per frame
#define NWG  (128 * NPT)          // 896 blocks, % 8 == 0
#define LROW 264                  // bf16 per LDS pixel row (528 B)

using bf16x8 = __attribute__((ext_vector_type(8))) short;
using bf16x4 = __attribute__((ext_vector_type(4))) short;
using f32x4  = __attribute__((ext_vector_type(4))) float;

static __device__ __forceinline__ unsigned int pk2(float lo, float hi) {
    union { __hip_bfloat162 h; unsigned int u; } cv;
    cv.h = __float22bfloat162_rn(make_float2(lo, hi));
    return cv.u;
}

// ---- W f32 -> bf16 row-major (one-shot) ------------------------------------
__global__ void wconv(const float* __restrict__ w, unsigned short* __restrict__ wb) {
    const int i = (blockIdx.x * 256 + threadIdx.x) * 4;
    f32x4 v = *(const f32x4*)(w + i);
    *(uint2*)(wb + i) = make_uint2(pk2(v[0], v[1]), pk2(v[2], v[3]));
}

__global__ __launch_bounds__(512, 4)   // 128-reg cap; 2 blocks/CU (LDS), 16 waves/CU
void tsm_f512(const float* __restrict__ x,
              const unsigned short* __restrict__ wb,
              float* __restrict__ out) {
    __shared__ __align__(16) unsigned short y[P_TILE * LROW];   // 59136 B

    const int bid = blockIdx.x;
    const int wg  = (bid & 7) * (NWG / 8) + (bid >> 3);   // XCD-bijective
    const int n   = wg / NPT;             // frame
    const int pt  = wg - n * NPT;
    const int p0  = pt * P_TILE;
    const int tid = threadIdx.x;
    const int tf  = n & 7;

    const int lane = tid & 63;
    const int wv   = tid >> 6;            // 8 waves x 32 out-channels
    const int g    = lane >> 4;
    const int ol   = lane & 15;

    // ---- staging constants: thread owns channel pair (2cpg, 2cpg+1), 28 px
    const int cpg = tid >> 2;             // 0..127
    const int pvs = tid & 3;              // pv = pvs + 4i, i = 0..6
    const int c0  = cpg * 2;
    const int d   = (cpg < 16) ? -1 : (cpg < 32 ? 1 : 0);
    const bool valid = !((d == -1 && tf == 0) || (d == 1 && tf == 7));
    const float* sbase = x + ((size_t)(n + (valid ? d : 0)) * CDIM + c0) * HWPX
                           + p0 + pvs * 4;

    bf16x8 wf[4][2];                      // current K-half W frags (32 regs)
    f32x4  r0[7], r1[7];
    f32x4  acc[2][7];

    #define WISSUE(PASS)                                                       \
    {                                                                          \
        _Pragma("unroll")                                                      \
        for (int kh = 0; kh < 4; ++kh)                                         \
            _Pragma("unroll")                                                  \
            for (int m = 0; m < 2; ++m) {                                      \
                const unsigned short* wp_ =                                    \
                    &wb[(size_t)(wv * 32 + m * 16 + ol) * CDIM                 \
                        + ((PASS) * 4 + kh) * 32 + g * 8];                     \
                asm volatile("global_load_dwordx4 %0, %1, off"                 \
                             : "=v"(wf[kh][m]) : "v"(wp_));                    \
            }                                                                  \
    }

    // swapped operands: D[p,o] = mfma(Y-frag, W-frag); acc row=g*4+r -> pixel
    #define COMPUTE(PASS)                                                      \
    {                                                                          \
        _Pragma("unroll")                                                      \
        for (int nn = 0; nn < 7; ++nn) {                                       \
            const int lp   = nn * 16 + ol;                                     \
            const int zz   = ((lp >> 3) & 7) << 2;                             \
            const int rowb = lp * LROW;                                        \
            _Pragma("unroll")                                                  \
            for (int kh = 0; kh < 4; ++kh) {                                   \
                const int c  = ((PASS) * 4 + kh) * 32 + g * 8;                 \
                const int e0 = c ^ zz;                                         \
                const bf16x4 lo = *(const bf16x4*)&y[rowb + e0];               \
                const bf16x4 hi = *(const bf16x4*)&y[rowb + (e0 ^ 4)];         \
                const bf16x8 bf = __builtin_shufflevector(lo, hi,              \
                                                          0, 1, 2, 3, 4, 5, 6, 7); \
                _Pragma("unroll")                                              \
                for (int m = 0; m < 2; ++m)                                    \
                    acc[m][nn] = __builtin_amdgcn_mfma_f32_16x16x32_bf16(      \
                        bf, wf[kh][m], acc[m][nn], 0, 0, 0);                   \
            }                                                                  \
        }                                                                      \
    }

    // ---- prologue: 14 staging loads + wfA, single LDS write + barrier -----
    #pragma unroll
    for (int i = 0; i < 7; ++i) {
        const float* s = sbase + 16 * i;           // pv = pvs + 4i
        asm volatile("global_load_dwordx4 %0, %1, off" : "=v"(r0[i]) : "v"(s));
        const float* s1 = s + HWPX;
        asm volatile("global_load_dwordx4 %0, %1, off" : "=v"(r1[i]) : "v"(s1));
    }
    WISSUE(0)

    asm volatile("s_waitcnt vmcnt(8)" ::: "memory");   // staging done, wfA flying
    __builtin_amdgcn_sched_barrier(0);
    #pragma unroll
    for (int i = 0; i < 7; ++i) {
        const int pv = pvs + 4 * i;
        const int cc = c0 ^ (((pv >> 1) & 7) << 2);
        const int rb = pv * 4 * LROW + cc;
        #pragma unroll
        for (int r = 0; r < 4; ++r)
            *(unsigned int*)&y[rb + r * LROW] =
                valid ? pk2(r0[i][r], r1[i][r]) : 0u;
    }
    __syncthreads();

    asm volatile("s_waitcnt vmcnt(0)" ::: "memory");   // wfA ready
    __builtin_amdgcn_sched_barrier(0);

    #pragma unroll
    for (int m = 0; m < 2; ++m)
        #pragma unroll
        for (int nn = 0; nn < 7; ++nn)
            acc[m][nn] = f32x4{0.f, 0.f, 0.f, 0.f};

    COMPUTE(0)                                         // c < 128

    WISSUE(1)                                          // WAR-safe in program order
    asm volatile("s_waitcnt vmcnt(0)" ::: "memory");   // wfB ready (~L2 latency,
    __builtin_amdgcn_sched_barrier(0);                 //  covered by 16 waves/CU)

    COMPUTE(1)                                         // c >= 128

    // ---- stores: D[p,o] -> 14 dwordx4 per thread --------------------------
    #pragma unroll
    for (int m = 0; m < 2; ++m) {
        const int o = wv * 32 + m * 16 + ol;
        float* ob = out + (size_t)n * FRST + (size_t)o * HWPX + p0 + g * 4;
        #pragma unroll
        for (int nn = 0; nn < 7; ++nn)
            *(f32x4*)(ob + nn * 16) = acc[m][nn];
    }

    #undef WISSUE
    #undef COMPUTE
}

// ---- fallback (no workspace): R3 kernel, known-correct ---------------------
#define LDS_STRIDE 264
__global__ __launch_bounds__(512, 4)
void tsm_fallback(const float* __restrict__ x, const float* __restrict__ w,
                  float* __restrict__ out) {
    __shared__ __align__(16) unsigned short ylds[P_TILE * LDS_STRIDE];
    const int n = blockIdx.x, tile = blockIdx.y, p0 = tile * P_TILE;
    const int tid = threadIdx.x, tf = n & 7;
    f32x4 v0[7], v1[7]; int cps[7], pvs[7];
    #pragma unroll
    for (int i = 0; i < 7; ++i) {
        const int idx = tid + i * 512, cp = idx / 28, pv = idx - cp * 28;
        cps[i] = cp; pvs[i] = pv;
        const int c0 = cp * 2;
        int nsrc; bool valid;
        if (c0 < 32)      { nsrc = n - 1; valid = (tf > 0); }
        else if (c0 < 64) { nsrc = n + 1; valid = (tf < 7); }
        else              { nsrc = n;     valid = true; }
        const float* src = x + ((size_t)(valid ? nsrc : n) * CDIM + c0) * HWPX + p0 + pv * 4;
        f32x4 a = {0,0,0,0}, b = {0,0,0,0};
        if (valid) { a = *(const f32x4*)src; b = *(const f32x4*)(src + HWPX); }
        v0[i] = a; v1[i] = b;
    }
    #pragma unroll
    for (int i = 0; i < 7; ++i) {
        const int c0 = cps[i] * 2, pv = pvs[i];
        const int cc = c0 ^ ((pv & 7) << 3);
        const int rb = pv * 4 * LDS_STRIDE + cc;
        #pragma unroll
        for (int r = 0; r < 4; ++r)
            *(unsigned int*)&ylds[rb + r * LDS_STRIDE] = pk2(v0[i][r], v1[i][r]);
    }
    __syncthreads();
    const int lane = tid & 63, wv = tid >> 6, g = lane >> 4, ol = lane & 15;
    f32x4 acc[2][7];
    #pragma unroll
    for (int m = 0; m < 2; ++m)
        #pragma unroll
        for (int nn = 0; nn < 7; ++nn) acc[m][nn] = f32x4{0,0,0,0};
    #pragma unroll
    for (int kk = 0; kk < 8; ++kk) {
        const int c = kk * 32 + g * 8;
        bf16x8 af[2];
        #pragma unroll
        for (int m = 0; m < 2; ++m) {
            const float* wp = w + (size_t)(wv * 32 + m * 16 + ol) * CDIM + c;
            f32x4 w0 = *(const f32x4*)wp, w1 = *(const f32x4*)(wp + 4);
            union { bf16x8 v; unsigned int u4[4]; } cv;
            cv.u4[0] = pk2(w0[0], w0[1]); cv.u4[1] = pk2(w0[2], w0[3]);
            cv.u4[2] = pk2(w1[0], w1[1]); cv.u4[3] = pk2(w1[2], w1[3]);
            af[m] = cv.v;
        }
        #pragma unroll
        for (int nn = 0; nn < 7; ++nn) {
            const int p = nn * 16 + ol;
            const int cc = c ^ (((p >> 2) & 7) << 3);
            const bf16x8 bf = *(const bf16x8*)&ylds[p * LDS_STRIDE + cc];
            #pragma unroll
            for (int m = 0; m < 2; ++m)
                acc[m][nn] = __builtin_amdgcn_mfma_f32_16x16x32_bf16(af[m], bf, acc[m][nn], 0, 0, 0);
        }
    }
    const size_t outbase = (size_t)n * CDIM * HWPX + p0 + ol;
    #pragma unroll
    for (int m = 0; m < 2; ++m)
        #pragma unroll
        for (int r = 0; r < 4; ++r) {
            const int o = wv * 32 + m * 16 + g * 4 + r;
            float* orow = out + outbase + (size_t)o * HWPX;
            #pragma unroll
            for (int nn = 0; nn < 7; ++nn) orow[nn * 16] = acc[m][nn][r];
        }
}

extern "C" void kernel_launch(void* const* d_in, const int* in_sizes, int n_in,
                              void* d_out, int out_size, void* d_ws, size_t ws_size,
                              hipStream_t stream) {
    const float* x = (const float*)d_in[0];
    const float* w = (const float*)d_in[1];
    float* out     = (float*)d_out;
    const size_t wb_bytes = (size_t)CDIM * CDIM * sizeof(unsigned short); // 128KB
    if (ws_size >= wb_bytes) {
        unsigned short* wbuf = (unsigned short*)d_ws;
        wconv<<<64, 256, 0, stream>>>(w, wbuf);
        tsm_f512<<<NWG, 512, 0, stream>>>(x, wbuf, out);
    } else {
        tsm_fallback<<<dim3(128, 7, 1), dim3(512, 1, 1), 0, stream>>>(x, w, out);
    }
}

// Round 16
// 48.587 us; speedup vs baseline: 1.3032x; 1.3032x over previous
//
#include <hip/hip_runtime.h>
#include <hip/hip_bf16.h>

// TSM temporal shift + 1x1 conv (256->256) fused as bf16 MFMA GEMM.
// x: [128, 256, 28, 28] f32, w: [256, 256] f32, out: [128, 256, 28, 28] f32.
// out[n,o,p] = sum_c W[o,c] * Y_n[c,p],
//   Y_n[c,p] = x[n-1,c,p] (c<32, t>0), x[n+1,c,p] (32<=c<64, t<7), x[n,c,p] else.
//
// R16 = REVERT to R10 (best: 48.6us). Session evidence:
//  R12 (64px full-o), R13 (sequential o-halves), R14 (non-draining tail),
//  R15 (8-wave single-stage) each tried to remove R10's duplicate x read;
//  ALL regressed (61.6 / 58.0 / 56.2 / 63.3), each for a different measured
//  mechanism (exposed W drain / store-drain serialization / halved memory
//  duty / partial-line RMW write inflation). The duplicate read is L3-served
//  (FETCH identical with and without it); R10's HBM traffic is 150MB
//  (~3.1 TB/s) and its limiter is VMEM latency structure, which every
//  alternative structure made worse. R10 = empirical optimum.
//
// R10 structure: deep single-shot staging + K-split pipeline + 4-bf16 swizzle.
//  - Block = (frame, 112px tile, o-half); 1792 blocks, 256 thr / 4 waves.
//  - 28 asm global_load_dwordx4 back-to-back (28KB in flight/wave).
//  - K-split: vmcnt(14) -> write c<128 -> sync -> MFMA kk0..3 while c>=128
//    flies -> vmcnt(0) -> write -> sync -> MFMA kk4..7.
//  - Swizzle h(p)=((p>>3)&7)<<2: writes <=2-way, reads two ds_read_b64
//    at e0 / e0^4 (uniform 4/bank).
//  - W panel asm-pinned (AGPR-resident), zero global loads in compute.

#define CDIM 256
#define HWPX 784
#define FRST (CDIM * HWPX)        // 200704 floats per frame
#define P_TILE 112
#define NPT  7                    // 112-px tiles per frame
#define NWG  (128 * NPT * 2)      // 1792 blocks (x2 o-halves), % 8 == 0
#define LROW 264                  // bf16 per LDS pixel row (528 B)

using bf16x8 = __attribute__((ext_vector_type(8))) short;
using bf16x4 = __attribute__((ext_vector_type(4))) short;
using f32x4  = __attribute__((ext_vector_type(4))) float;

static __device__ __forceinline__ unsigned int pk2(float lo, float hi) {
    union { __hip_bfloat162 h; unsigned int u; } cv;
    cv.h = __float22bfloat162_rn(make_float2(lo, hi));
    return cv.u;
}

// ---- W f32 -> bf16 row-major (one-shot) ------------------------------------
__global__ void wconv(const float* __restrict__ w, unsigned short* __restrict__ wb) {
    const int i = (blockIdx.x * 256 + threadIdx.x) * 4;
    f32x4 v = *(const f32x4*)(w + i);
    *(uint2*)(wb + i) = make_uint2(pk2(v[0], v[1]), pk2(v[2], v[3]));
}

__global__ __launch_bounds__(256, 2)   // 256-reg budget, 2 blocks/CU (LDS-capped)
void tsm_ksplit(const float* __restrict__ x,
                const unsigned short* __restrict__ wb,
                float* __restrict__ out) {
    __shared__ __align__(16) unsigned short y[P_TILE * LROW];   // 59136 B

    const int bid = blockIdx.x;
    const int wg  = (bid & 7) * (NWG / 8) + (bid >> 3);   // XCD-bijective
    const int h    = wg & 1;              // o-half
    const int pair = wg >> 1;
    const int n    = pair / NPT;          // frame
    const int pt   = pair - n * NPT;
    const int p0   = pt * P_TILE;
    const int tid  = threadIdx.x;
    const int tf   = n & 7;

    const int lane = tid & 63;
    const int wv   = tid >> 6;
    const int g    = lane >> 4;
    const int ol   = lane & 15;

    // ---- W panel (asm-pinned once; drained at the first vmcnt) ------------
    bf16x8 wf[8][2];
    #pragma unroll
    for (int kk = 0; kk < 8; ++kk)
        #pragma unroll
        for (int m = 0; m < 2; ++m) {
            const unsigned short* wp =
                &wb[(size_t)(h * 128 + wv * 32 + m * 16 + ol) * CDIM + kk * 32 + g * 8];
            asm volatile("global_load_dwordx4 %0, %1, off"
                         : "=v"(wf[kk][m]) : "v"(wp));
        }

    // ---- staging: all 28 loads issued; items i<7 == channels 0..127 -------
    f32x4 r0[14], r1[14];
    #pragma unroll
    for (int i = 0; i < 14; ++i) {
        const int idx = tid + i * 256;
        const int cp  = idx / 28;                 // magic-mul
        const int pv  = idx - cp * 28;
        const int c0  = cp * 2;
        const int d   = (cp < 16) ? -1 : (cp < 32 ? 1 : 0);
        const bool valid = !((d == -1 && tf == 0) || (d == 1 && tf == 7));
        const float* s = x + ((size_t)(n + (valid ? d : 0)) * CDIM + c0) * HWPX
                           + p0 + pv * 4;
        asm volatile("global_load_dwordx4 %0, %1, off" : "=v"(r0[i]) : "v"(s));
        const float* s1 = s + HWPX;
        asm volatile("global_load_dwordx4 %0, %1, off" : "=v"(r1[i]) : "v"(s1));
    }

    #define WRITE_ITEM(i)                                                      \
    {                                                                          \
        const int idx = tid + (i) * 256;                                       \
        const int cp  = idx / 28;                                              \
        const int pv  = idx - cp * 28;                                         \
        const int c0  = cp * 2;                                                \
        const int d   = (cp < 16) ? -1 : (cp < 32 ? 1 : 0);                    \
        const bool valid = !((d == -1 && tf == 0) || (d == 1 && tf == 7));     \
        const int cc  = c0 ^ (((pv >> 1) & 7) << 2);  /* h(p), p=pv*4+r */     \
        const int rb  = pv * 4 * LROW + cc;                                    \
        _Pragma("unroll")                                                      \
        for (int r = 0; r < 4; ++r)                                            \
            *(unsigned int*)&y[rb + r * LROW] =                                \
                valid ? pk2(r0[i][r], r1[i][r]) : 0u;                          \
    }

    // wait wf(16) + first 14 loads; newest 14 (c>=128) stay in flight
    asm volatile("s_waitcnt vmcnt(14)" ::: "memory");
    __builtin_amdgcn_sched_barrier(0);
    #pragma unroll
    for (int i = 0; i < 7; ++i) WRITE_ITEM(i)
    __syncthreads();

    f32x4 acc[2][7];
    #pragma unroll
    for (int m = 0; m < 2; ++m)
        #pragma unroll
        for (int nn = 0; nn < 7; ++nn)
            acc[m][nn] = f32x4{0.f, 0.f, 0.f, 0.f};

    #define COMPUTE(K0, K1)                                                    \
    {                                                                          \
        _Pragma("unroll")                                                      \
        for (int nn = 0; nn < 7; ++nn) {                                       \
            const int p    = nn * 16 + ol;                                     \
            const int zz   = ((p >> 3) & 7) << 2;                              \
            const int rowb = p * LROW;                                         \
            _Pragma("unroll")                                                  \
            for (int kk = (K0); kk < (K1); ++kk) {                             \
                const int c  = kk * 32 + g * 8;                                \
                const int e0 = c ^ zz;                                         \
                const bf16x4 lo = *(const bf16x4*)&y[rowb + e0];               \
                const bf16x4 hi = *(const bf16x4*)&y[rowb + (e0 ^ 4)];         \
                const bf16x8 bf = __builtin_shufflevector(lo, hi,              \
                                                          0, 1, 2, 3, 4, 5, 6, 7); \
                acc[0][nn] = __builtin_amdgcn_mfma_f32_16x16x32_bf16(          \
                    wf[kk][0], bf, acc[0][nn], 0, 0, 0);                       \
                acc[1][nn] = __builtin_amdgcn_mfma_f32_16x16x32_bf16(          \
                    wf[kk][1], bf, acc[1][nn], 0, 0, 0);                       \
            }                                                                  \
        }                                                                      \
    }

    // ---- pass 1: kk 0..3 (columns < 128) while half-2 loads fly -----------
    COMPUTE(0, 4)

    // ---- half 2 arrives; write columns 128..255 (disjoint, no read race) --
    asm volatile("s_waitcnt vmcnt(0)" ::: "memory");
    __builtin_amdgcn_sched_barrier(0);
    #pragma unroll
    for (int i = 7; i < 14; ++i) WRITE_ITEM(i)
    __syncthreads();

    // ---- pass 2: kk 4..7, accumulate into same acc ------------------------
    COMPUTE(4, 8)

    // ---- epilogue: C/D col=lane&15 (pixel), row=(lane>>4)*4+r (channel) ---
    const size_t outbase = (size_t)n * CDIM * HWPX + p0 + ol;
    #pragma unroll
    for (int m = 0; m < 2; ++m) {
        #pragma unroll
        for (int r = 0; r < 4; ++r) {
            const int o = h * 128 + wv * 32 + m * 16 + g * 4 + r;
            float* orow = out + outbase + (size_t)o * HWPX;
            #pragma unroll
            for (int nn = 0; nn < 7; ++nn)
                orow[nn * 16] = acc[m][nn][r];
        }
    }
    #undef WRITE_ITEM
    #undef COMPUTE
}

// ---- fallback (no workspace): R3 kernel, known-correct ---------------------
#define LDS_STRIDE 264
__global__ __launch_bounds__(512, 4)
void tsm_fallback(const float* __restrict__ x, const float* __restrict__ w,
                  float* __restrict__ out) {
    __shared__ __align__(16) unsigned short ylds[P_TILE * LDS_STRIDE];
    const int n = blockIdx.x, tile = blockIdx.y, p0 = tile * P_TILE;
    const int tid = threadIdx.x, tf = n & 7;
    f32x4 v0[7], v1[7]; int cps[7], pvs[7];
    #pragma unroll
    for (int i = 0; i < 7; ++i) {
        const int idx = tid + i * 512, cp = idx / 28, pv = idx - cp * 28;
        cps[i] = cp; pvs[i] = pv;
        const int c0 = cp * 2;
        int nsrc; bool valid;
        if (c0 < 32)      { nsrc = n - 1; valid = (tf > 0); }
        else if (c0 < 64) { nsrc = n + 1; valid = (tf < 7); }
        else              { nsrc = n;     valid = true; }
        const float* src = x + ((size_t)(valid ? nsrc : n) * CDIM + c0) * HWPX + p0 + pv * 4;
        f32x4 a = {0,0,0,0}, b = {0,0,0,0};
        if (valid) { a = *(const f32x4*)src; b = *(const f32x4*)(src + HWPX); }
        v0[i] = a; v1[i] = b;
    }
    #pragma unroll
    for (int i = 0; i < 7; ++i) {
        const int c0 = cps[i] * 2, pv = pvs[i];
        const int cc = c0 ^ ((pv & 7) << 3);
        const int rb = pv * 4 * LDS_STRIDE + cc;
        #pragma unroll
        for (int r = 0; r < 4; ++r)
            *(unsigned int*)&ylds[rb + r * LDS_STRIDE] = pk2(v0[i][r], v1[i][r]);
    }
    __syncthreads();
    const int lane = tid & 63, wv = tid >> 6, g = lane >> 4, ol = lane & 15;
    f32x4 acc[2][7];
    #pragma unroll
    for (int m = 0; m < 2; ++m)
        #pragma unroll
        for (int nn = 0; nn < 7; ++nn) acc[m][nn] = f32x4{0,0,0,0};
    #pragma unroll
    for (int kk = 0; kk < 8; ++kk) {
        const int c = kk * 32 + g * 8;
        bf16x8 af[2];
        #pragma unroll
        for (int m = 0; m < 2; ++m) {
            const float* wp = w + (size_t)(wv * 32 + m * 16 + ol) * CDIM + c;
            f32x4 w0 = *(const f32x4*)wp, w1 = *(const f32x4*)(wp + 4);
            union { bf16x8 v; unsigned int u4[4]; } cv;
            cv.u4[0] = pk2(w0[0], w0[1]); cv.u4[1] = pk2(w0[2], w0[3]);
            cv.u4[2] = pk2(w1[0], w1[1]); cv.u4[3] = pk2(w1[2], w1[3]);
            af[m] = cv.v;
        }
        #pragma unroll
        for (int nn = 0; nn < 7; ++nn) {
            const int p = nn * 16 + ol;
            const int cc = c ^ (((p >> 2) & 7) << 3);
            const bf16x8 bf = *(const bf16x8*)&ylds[p * LDS_STRIDE + cc];
            #pragma unroll
            for (int m = 0; m < 2; ++m)
                acc[m][nn] = __builtin_amdgcn_mfma_f32_16x16x32_bf16(af[m], bf, acc[m][nn], 0, 0, 0);
        }
    }
    const size_t outbase = (size_t)n * CDIM * HWPX + p0 + ol;
    #pragma unroll
    for (int m = 0; m < 2; ++m)
        #pragma unroll
        for (int r = 0; r < 4; ++r) {
            const int o = wv * 32 + m * 16 + g * 4 + r;
            float* orow = out + outbase + (size_t)o * HWPX;
            #pragma unroll
            for (int nn = 0; nn < 7; ++nn) orow[nn * 16] = acc[m][nn][r];
        }
}

extern "C" void kernel_launch(void* const* d_in, const int* in_sizes, int n_in,
                              void* d_out, int out_size, void* d_ws, size_t ws_size,
                              hipStream_t stream) {
    const float* x = (const float*)d_in[0];
    const float* w = (const float*)d_in[1];
    float* out     = (float*)d_out;
    const size_t wb_bytes = (size_t)CDIM * CDIM * sizeof(unsigned short); // 128KB
    if (ws_size >= wb_bytes) {
        unsigned short* wbuf = (unsigned short*)d_ws;
        wconv<<<64, 256, 0, stream>>>(w, wbuf);
        tsm_ksplit<<<NWG, 256, 0, stream>>>(x, wbuf, out);
    } else {
        tsm_fallback<<<dim3(128, 7, 1), dim3(512, 1, 1), 0, stream>>>(x, w, out);
    }
}